// Round 3
// baseline (233.664 us; speedup 1.0000x reference)
//
#include <hip/hip_runtime.h>

// LIF activation: x [B=64, T=500, C=1024] fp32, scalars w_input, w_leak.
// Per (b,c): forget=(Vm<1); Vm=relu(wi*x_t + kl*Vm*forget); spike=(Vm>1).
// 65536 serial sequences -> 1024 compute waves (fixed by shape).
//
// History:
//  R1-R3: register staging — backend sinks bulk loads to uses. 82 us.
//  R4: LDS staging, global_load_lds + __syncthreads dbuf. 82 us, 2.4 TB/s.
//  R6: barrier-free counted-vmcnt, wave-private slices. 80.5 us. IDENTICAL
//      to R4 and R2 => sync discipline was never the limiter. Per-wave
//      effective BW ~1.3 B/cyc (~307 cyc/VMEM op) regardless of scheme:
//      per-wave MLP on a mixed load+narrow-store stream is the bottleneck.
//      Meanwhile fillBufferAligned hits 6.6 TB/s at the SAME ~9% occupancy
//      with wide pure stores -> the chip can, our wave op-mix can't.
//  R7 (this): attack the per-wave stream limit on both axes.
//      (a) producer/consumer: 512-thread blocks = 8 waves/CU. Waves 0-3 are
//          pure load streams (global_load_lds only, 3-deep prefetch, counted
//          VMWAIT(10) on a loads-only ledger). Waves 4-7 run the serial Vm
//          chain and stores — they never wait on loads (producer waits +
//          barrier transfer readiness).
//      (b) stores 4x wider: spikes staged in a wave-private [4][64] LDS
//          slice, flushed as global_store_dwordx4 (1 KB/instr, fill-kernel
//          class) -> 5 store ops/chunk/wave instead of 20.
//      One raw s_barrier per chunk (no vmcnt drain). All 8 waves execute
//      exactly 25 barriers; no conditional barrier paths.
//
// Producer vmcnt ledger (loads only, 5 per chunk, prologue stages 0,1,2):
//   iter k<=22: outstanding Lk,Lk+1,Lk+2 (15) -> VMWAIT(10) = Lk done
//   iter 23   : outstanding L23,L24     (10) -> VMWAIT(5)
//   iter 24   : outstanding L24          (5) -> VMWAIT(0)  (stale, instant)
// Buffer (k+3)%4 overwritten at iter k: consumers finished reading it
// (chunk k-1) upon arriving at barrier k; their lgkmcnt(0) before the
// barrier guarantees the ds_reads physically completed.
//
// __fmul_rn/__fadd_rn: spikes are exact step functions vs threshold 1.0;
// must match numpy's unfused fp32 op-by-op arithmetic (absmax=0 so far).

#define LIF_B 64
#define LIF_T 500
#define LIF_C 1024
#define LIF_TC 20                  // timesteps per chunk
#define LIF_NCH 25                 // 500 / 20
#define LIF_NBUF 4                 // x double... quad buffer (80 KB LDS)

typedef float vfloat4 __attribute__((ext_vector_type(4)));

// global_load_lds: per-lane global src, wave-uniform LDS base; HW writes
// LDS at base + lane*16. Launder generic->AS pointers via uintptr_t.
#define GLOBAL_AS(p) ((__attribute__((address_space(1))) const void*)(uintptr_t)(p))
#define LDS_AS(p)    ((__attribute__((address_space(3))) void*)(uintptr_t)(p))

#define VMWAIT(n) asm volatile("s_waitcnt vmcnt(" #n ")" ::: "memory")
#define LGKM0()   asm volatile("s_waitcnt lgkmcnt(0)" ::: "memory")
// Raw barrier (no implicit vmcnt(0) drain). Trailing empty asm blocks
// IR-level hoisting of subsequent memory ops above the barrier.
#define BARRIER() do { __builtin_amdgcn_s_barrier(); asm volatile("" ::: "memory"); } while (0)

__global__ __launch_bounds__(512) void lif_kernel(
    const float* __restrict__ x,
    const float* __restrict__ w_input_p,
    const float* __restrict__ w_leak_p,
    float* __restrict__ out) {

  // x chunks: [buf][slice][row*64+chan], wave-private slices. 80 KB.
  __shared__ __align__(16) float lds_x[LIF_NBUF][4][LIF_TC * 64];
  // spike staging: [slice][4 rows * 64 chans], wave-private. 4 KB.
  __shared__ __align__(16) float sp[4][4 * 64];

  const int b     = blockIdx.x >> 2;          // 64 b-rows
  const int cbase = (blockIdx.x & 3) << 8;    // 4 channel groups of 256
  const int tidx  = threadIdx.x;              // 0..511
  const int wave  = tidx >> 6;                // 0..7
  const int lane  = tidx & 63;
  const bool producer = wave < 4;
  const int w = wave & 3;                     // slice id for both roles

  const float wi = w_input_p[0];
  const float kl = __fsub_rn(1.0f, w_leak_p[0]);  // 1 - w_leak
  // Drain arg loads so the producer vmcnt ledger starts from zero.
  asm volatile("s_waitcnt vmcnt(0) lgkmcnt(0)" ::: "memory");

  const float* xblk = x   + (size_t)b * LIF_T * LIF_C + cbase;
  float*       oblk = out + (size_t)b * LIF_T * LIF_C + cbase;

  // Producer wave w stages chunk k's channels [64w,64w+64) into slice w of
  // lds_x[p]: 5 load_lds, each 4 rows x 16 chans-of-16B. Lane l: global row
  // r0+(l>>4), chan 64w+(l&15)*4; LDS lands at slice + l*16 B, i.e.
  // row-major [20][64] (l*4 floats == (l>>4)*64 + (l&15)*4). Verified
  // absmax=0 in R6.
  auto stage = [&](int k, int p) {
    const float* src0 = xblk + (size_t)k * LIF_TC * LIF_C
                      + (w << 6) + ((lane & 15) << 2);
#pragma unroll
    for (int r0 = 0; r0 < LIF_TC; r0 += 4) {
      const float* g = src0 + (size_t)(r0 + (lane >> 4)) * LIF_C;
      float* l = &lds_x[p][w][r0 * 64];                // wave-uniform base
      __builtin_amdgcn_global_load_lds(GLOBAL_AS(g), LDS_AS(l), 16, 0, 0);
    }
    __builtin_amdgcn_sched_barrier(0);   // keep the 5 issues as one cluster
  };

  float Vm = 0.0f;

  if (producer) { stage(0, 0); stage(1, 1); stage(2, 2); }

  for (int k = 0; k < LIF_NCH; ++k) {
    if (producer) {
      if (k <= LIF_NCH - 3)      VMWAIT(10);  // chunk k's 5 loads done
      else if (k == LIF_NCH - 2) VMWAIT(5);
      else                       VMWAIT(0);   // stale by >2 chunks: instant
    } else {
      LGKM0();   // my ds_reads of buf (k-1)&3 completed -> safe to overwrite
    }
    BARRIER();

    if (producer) {
      if (k + 3 < LIF_NCH) stage(k + 3, (k + 3) & 3);
    } else {
      const int p = k & 3;
      float* obase = oblk + (size_t)k * LIF_TC * LIF_C + (w << 6);
#pragma unroll
      for (int r0 = 0; r0 < LIF_TC; r0 += 4) {
#pragma unroll
        for (int dr = 0; dr < 4; ++dr) {
          const float xt  = lds_x[p][w][(r0 + dr) * 64 + lane];
          const float acc = (Vm < 1.0f) ? __fmul_rn(kl, Vm) : 0.0f;
          const float v   = __fadd_rn(__fmul_rn(wi, xt), acc);
          Vm = fmaxf(v, 0.0f);
          sp[w][dr * 64 + lane] = (Vm > 1.0f) ? 1.0f : 0.0f;
        }
        // Flush 4 rows x 64 chans as one dwordx4 per lane: lane l covers
        // row r0+(l>>4), chans (l&15)*4..+4 of this wave's 64-chan slice.
        const vfloat4 v4 =
            *reinterpret_cast<const vfloat4*>(&sp[w][lane << 2]);
        float* gdst = obase + (size_t)(r0 + (lane >> 4)) * LIF_C
                    + ((lane & 15) << 2);
        __builtin_nontemporal_store(v4, reinterpret_cast<vfloat4*>(gdst));
      }
      __builtin_amdgcn_sched_barrier(0);   // stores stay inside this region
    }
  }
}

extern "C" void kernel_launch(void* const* d_in, const int* in_sizes, int n_in,
                              void* d_out, int out_size, void* d_ws, size_t ws_size,
                              hipStream_t stream) {
  const float* x  = (const float*)d_in[0];
  const float* wi = (const float*)d_in[1];
  const float* wl = (const float*)d_in[2];
  float* out = (float*)d_out;

  const int grid = LIF_B * (LIF_C / 256);  // 64 * 4 = 256 blocks, 1/CU
  lif_kernel<<<grid, 512, 0, stream>>>(x, wi, wl, out);
}